// Round 1
// baseline (7228.072 us; speedup 1.0000x reference)
//
#include <hip/hip_runtime.h>

#define THREADS 256
#define QCAP 1024
#define KC 64
#define LDST 68  // LDS row stride in floats (64 + 4 pad)
#define INF_F __builtin_inff()

__device__ __forceinline__ bool lexLess(float s1, int n1, float s2, int n2) {
    return (s1 < s2) || (s1 == s2 && n1 < n2);
}

// Kernel 1: fused distance (s = ||y||^2 - 2 x.y, per-row constant ||x||^2 omitted)
// + per-block exact top-16 per batch row (lexicographic (s, idx)).
__global__ __launch_bounds__(THREADS) void dist_topk_kernel(
    const float* __restrict__ brep,   // [64,512]
    const float* __restrict__ reps,   // [N,512]
    float* __restrict__ cs, int* __restrict__ ci,
    int N, int chunk)
{
    __shared__ __align__(16) float As[64][LDST];
    __shared__ __align__(16) float Bs[64][LDST];
    __shared__ float qs[QCAP];
    __shared__ int   qp[QCAP];
    __shared__ float topd[64][16];
    __shared__ int   topi[64][16];
    __shared__ float thr[64];
    __shared__ int   thrn[64];
    __shared__ int   cnt[64];
    __shared__ float ynp[64][4];
    __shared__ float ys[64];
    __shared__ int   qcount;
    __shared__ int   flagPend;

    const int tid = threadIdx.x;
    const int nStart = blockIdx.x * chunk;
    const int nEnd = min(N, nStart + chunk);

    if (tid < 64) { thr[tid] = INF_F; thrn[tid] = 0x7fffffff; cnt[tid] = 0; }
    if (tid == 0) { qcount = 0; flagPend = 0; }
    __syncthreads();

    const int tm = tid & 15;    // 0..15, m = tm + 16*mi
    const int tn = tid >> 4;    // 0..15, n = tn + 16*ni
    const int srow = tid >> 2;  // staging row 0..63
    const int sq = tid & 3;     // staging quarter

    for (int n0 = nStart; n0 < nEnd; n0 += 64) {
        float acc[4][4] = {};
        float ynloc = 0.f;

        for (int kc = 0; kc < 512; kc += KC) {
            __syncthreads();
            // stage As (batch, L2-hot) and Bs (reps, streamed) + norm partials
            #pragma unroll
            for (int i = 0; i < 4; i++) {
                const int c4 = sq * 4 + i;  // f4 index within row, 0..15
                const float4 av = *(const float4*)(&brep[(size_t)srow * 512 + kc + c4 * 4]);
                *(float4*)(&As[srow][c4 * 4]) = av;
                const int n = n0 + srow;
                float4 bv = make_float4(0.f, 0.f, 0.f, 0.f);
                if (n < nEnd) bv = *(const float4*)(&reps[(size_t)n * 512 + kc + c4 * 4]);
                *(float4*)(&Bs[srow][c4 * 4]) = bv;
                ynloc = fmaf(bv.x, bv.x, ynloc);
                ynloc = fmaf(bv.y, bv.y, ynloc);
                ynloc = fmaf(bv.z, bv.z, ynloc);
                ynloc = fmaf(bv.w, bv.w, ynloc);
            }
            __syncthreads();
            // 4x4 register-blocked dot accumulation
            #pragma unroll 4
            for (int kq = 0; kq < 16; kq++) {
                const int k = kq * 4;
                float4 A0 = *(const float4*)(&As[tm][k]);
                float4 A1 = *(const float4*)(&As[tm + 16][k]);
                float4 A2 = *(const float4*)(&As[tm + 32][k]);
                float4 A3 = *(const float4*)(&As[tm + 48][k]);
                float4 B0 = *(const float4*)(&Bs[tn][k]);
                float4 B1 = *(const float4*)(&Bs[tn + 16][k]);
                float4 B2 = *(const float4*)(&Bs[tn + 32][k]);
                float4 B3 = *(const float4*)(&Bs[tn + 48][k]);
                float4 Af[4] = {A0, A1, A2, A3};
                float4 Bf[4] = {B0, B1, B2, B3};
                #pragma unroll
                for (int mi = 0; mi < 4; mi++) {
                    #pragma unroll
                    for (int ni = 0; ni < 4; ni++) {
                        acc[mi][ni] = fmaf(Af[mi].x, Bf[ni].x, acc[mi][ni]);
                        acc[mi][ni] = fmaf(Af[mi].y, Bf[ni].y, acc[mi][ni]);
                        acc[mi][ni] = fmaf(Af[mi].z, Bf[ni].z, acc[mi][ni]);
                        acc[mi][ni] = fmaf(Af[mi].w, Bf[ni].w, acc[mi][ni]);
                    }
                }
            }
        }

        // finalize row norms for this tile (deterministic fixed-order sum)
        ynp[srow][sq] = ynloc;
        __syncthreads();
        if (tid < 64) ys[tid] = (ynp[tid][0] + ynp[tid][1]) + (ynp[tid][2] + ynp[tid][3]);
        __syncthreads();

        // candidate values s = ||y||^2 - 2 x.y  (||x||^2 added in merge; constant per row)
        unsigned done = 0;
        float sv[4][4];
        #pragma unroll
        for (int ni = 0; ni < 4; ni++) {
            const int nl = tn + 16 * ni;
            const int n = n0 + nl;
            #pragma unroll
            for (int mi = 0; mi < 4; mi++) {
                sv[mi][ni] = fmaf(-2.f, acc[mi][ni], ys[nl]);
                if (n >= nEnd) done |= 1u << (mi * 4 + ni);
            }
        }

        // append/drain rounds (overflow-safe retry; content is order-independent)
        bool morework = true;
        while (morework) {
            if (tid == 0) flagPend = 0;
            __syncthreads();  // A: flag reset + prev qcount reset visible
            if (done != 0xFFFFu) {
                #pragma unroll
                for (int mi = 0; mi < 4; mi++) {
                    #pragma unroll
                    for (int ni = 0; ni < 4; ni++) {
                        const unsigned bit = 1u << (mi * 4 + ni);
                        if (done & bit) continue;
                        const int m = tm + 16 * mi;
                        const int n = n0 + tn + 16 * ni;
                        const float s = sv[mi][ni];
                        if (!lexLess(s, n, thr[m], thrn[m])) { done |= bit; continue; }
                        const int pos = atomicAdd(&qcount, 1);
                        if (pos < QCAP) { qs[pos] = s; qp[pos] = (m << 20) | n; done |= bit; }
                        else flagPend = 1;
                    }
                }
            }
            __syncthreads();  // B: appends done
            const int qn = min(qcount, QCAP);
            const bool any = (flagPend != 0);
            if (tid < 64 && qn > 0) {
                const int r = tid;
                int c = cnt[r];
                float tv = thr[r]; int tnn = thrn[r];
                for (int i = 0; i < qn; i++) {
                    const int u = qp[i];
                    if ((u >> 20) != r) continue;
                    const float s = qs[i]; const int n = u & 0xFFFFF;
                    if (c < 16) {
                        topd[r][c] = s; topi[r][c] = n; c++;
                        if (c == 16) {
                            tv = topd[r][0]; tnn = topi[r][0];
                            for (int j = 1; j < 16; j++)
                                if (!lexLess(topd[r][j], topi[r][j], tv, tnn)) { tv = topd[r][j]; tnn = topi[r][j]; }
                        }
                    } else if (lexLess(s, n, tv, tnn)) {
                        for (int j = 0; j < 16; j++)
                            if (topd[r][j] == tv && topi[r][j] == tnn) { topd[r][j] = s; topi[r][j] = n; break; }
                        tv = topd[r][0]; tnn = topi[r][0];
                        for (int j = 1; j < 16; j++)
                            if (!lexLess(topd[r][j], topi[r][j], tv, tnn)) { tv = topd[r][j]; tnn = topi[r][j]; }
                    }
                }
                cnt[r] = c; thr[r] = tv; thrn[r] = tnn;
            }
            __syncthreads();  // C: drain done; everyone has read flagPend/qcount
            if (tid == 0) qcount = 0;
            morework = any;
        }
    }

    // write per-block candidates (pad with +inf)
    if (tid < 64) {
        const int c = cnt[tid];
        const size_t base = ((size_t)blockIdx.x * 64 + tid) * 16;
        for (int j = 0; j < 16; j++) {
            cs[base + j] = (j < c) ? topd[tid][j] : INF_F;
            ci[base + j] = (j < c) ? topi[tid][j] : 0x7fffffff;
        }
    }
}

// Kernel 2: one block per batch row — exact global top-16 merge, sort,
// sqrt distances, softmax weights, action gather, outputs.
__global__ __launch_bounds__(256) void merge_kernel(
    const float* __restrict__ cs, const int* __restrict__ ci,
    const float* __restrict__ brep, const float* __restrict__ acts,
    float* __restrict__ out, int NBLK, int BA)
{
    const int r = blockIdx.x;
    const int tid = threadIdx.x;
    __shared__ float Ss[4096];
    __shared__ int   Si[4096];
    __shared__ float S2s[1024];
    __shared__ int   S2i[1024];
    __shared__ float xp[128];

    if (tid < 128) {
        const float* p = &brep[(size_t)r * 512 + tid * 4];
        xp[tid] = fmaf(p[0], p[0], fmaf(p[1], p[1], fmaf(p[2], p[2], p[3] * p[3])));
    }

    float ls[16]; int li[16];
    #pragma unroll
    for (int j = 0; j < 16; j++) { ls[j] = INF_F; li[j] = 0x7fffffff; }
    float mv = INF_F; int mn = 0x7fffffff; int mp = 0;

    const int total = NBLK * 16;
    for (int e = tid; e < total; e += 256) {
        const int blk = e >> 4, j = e & 15;
        const size_t a = (size_t)blk * 1024 + (size_t)r * 16 + j;
        const float s = cs[a]; const int n = ci[a];
        if (lexLess(s, n, mv, mn)) {
            ls[mp] = s; li[mp] = n;
            mv = ls[0]; mn = li[0]; mp = 0;
            #pragma unroll
            for (int q = 1; q < 16; q++)
                if (!lexLess(ls[q], li[q], mv, mn)) { mv = ls[q]; mn = li[q]; mp = q; }
        }
    }
    #pragma unroll
    for (int j = 0; j < 16; j++) { Ss[tid * 16 + j] = ls[j]; Si[tid * 16 + j] = li[j]; }
    __syncthreads();

    if (tid < 64) {
        #pragma unroll
        for (int j = 0; j < 16; j++) { ls[j] = INF_F; li[j] = 0x7fffffff; }
        mv = INF_F; mn = 0x7fffffff; mp = 0;
        for (int e = tid * 64; e < tid * 64 + 64; e++) {
            const float s = Ss[e]; const int n = Si[e];
            if (lexLess(s, n, mv, mn)) {
                ls[mp] = s; li[mp] = n;
                mv = ls[0]; mn = li[0]; mp = 0;
                #pragma unroll
                for (int q = 1; q < 16; q++)
                    if (!lexLess(ls[q], li[q], mv, mn)) { mv = ls[q]; mn = li[q]; mp = q; }
            }
        }
        #pragma unroll
        for (int j = 0; j < 16; j++) { S2s[tid * 16 + j] = ls[j]; S2i[tid * 16 + j] = li[j]; }
    }
    __syncthreads();

    if (tid == 0) {
        float fs[16]; int fi[16];
        #pragma unroll
        for (int j = 0; j < 16; j++) { fs[j] = INF_F; fi[j] = 0x7fffffff; }
        for (int e = 0; e < 1024; e++) {
            const float s = S2s[e]; const int n = S2i[e];
            if (lexLess(s, n, fs[15], fi[15])) {
                int p = 15;
                while (p > 0 && lexLess(s, n, fs[p - 1], fi[p - 1])) {
                    fs[p] = fs[p - 1]; fi[p] = fi[p - 1]; p--;
                }
                fs[p] = s; fi[p] = n;
            }
        }
        float xn = 0.f;
        for (int i = 0; i < 128; i++) xn += xp[i];
        float d[16], w[16], wsum = 0.f;
        for (int j = 0; j < 16; j++) d[j] = sqrtf(fmaxf(xn + fs[j], 0.f));
        for (int j = 0; j < 16; j++) { w[j] = expf(d[0] - d[j]); wsum += w[j]; }
        for (int a = 0; a < 7; a++) {
            float s = 0.f;
            for (int j = 0; j < 16; j++) s = fmaf(w[j], acts[(size_t)fi[j] * 7 + a], s);
            out[r * 7 + a] = s / wsum;
        }
        for (int j = 0; j < 16; j++) out[BA + r * 16 + j] = (float)fi[j];
    }
}

extern "C" void kernel_launch(void* const* d_in, const int* in_sizes, int n_in,
                              void* d_out, int out_size, void* d_ws, size_t ws_size,
                              hipStream_t stream) {
    const float* brep = (const float*)d_in[0];
    const float* reps = (const float*)d_in[1];
    const float* acts = (const float*)d_in[2];
    const int D = 512;
    const int B = in_sizes[0] / D;   // 64
    const int N = in_sizes[1] / D;   // 500000
    const int A = in_sizes[2] / N;   // 7
    float* out = (float*)d_out;

    const size_t perblk = (size_t)B * 16 * 8;  // cs+ci bytes per dist-block
    int NBLK = (int)(ws_size / perblk);
    if (NBLK > 768) NBLK = 768;   // 3 blocks/CU x 256 CU
    if (NBLK < 1) NBLK = 1;
    const int chunk = (N + NBLK - 1) / NBLK;

    float* cs = (float*)d_ws;
    int* ci = (int*)((char*)d_ws + (size_t)NBLK * B * 16 * 4);

    dist_topk_kernel<<<NBLK, THREADS, 0, stream>>>(brep, reps, cs, ci, N, chunk);
    merge_kernel<<<B, 256, 0, stream>>>(cs, ci, brep, acts, out, NBLK, B * A);
}

// Round 2
// 1574.367 us; speedup vs baseline: 4.5911x; 4.5911x over previous
//
#include <hip/hip_runtime.h>
#include <stdint.h>

typedef _Float16 f16;
typedef _Float16 f16x8 __attribute__((ext_vector_type(8)));
typedef float f32x4 __attribute__((ext_vector_type(4)));

#define INF_F __builtin_inff()
#define KM 24   // merge candidate margin

__device__ __forceinline__ bool lexLess(float s1, int n1, float s2, int n2) {
    return (s1 < s2) || (s1 == s2 && n1 < n2);
}

#define GLOAD_LDS16(gsrc, ldst)                                                  \
    __builtin_amdgcn_global_load_lds(                                            \
        (const __attribute__((address_space(1))) uint32_t*)(gsrc),               \
        (__attribute__((address_space(3))) uint32_t*)(ldst), 16, 0, 0)

// ---------------------------------------------------------------------------
// Kernel 0: pack brep [64,512] f32 into MFMA A-fragments (f16), fragment-linear.
// A layout for mfma_f32_16x16x32_f16: lane holds A[m=lane&15][k = 8*(lane>>4)+j].
// xfrag[((ms*16 + ks)*64 + lane)] : uint4 (8 f16), ms=m/16 (4), ks=k/32 (16).
// ---------------------------------------------------------------------------
__global__ __launch_bounds__(256) void prepack_kernel(
    const float* __restrict__ brep, uint4* __restrict__ xfrag)
{
    const int tid = blockIdx.x * 256 + threadIdx.x;   // 0..4095
    if (tid >= 4096) return;
    const int lane = tid & 63;
    const int ks = (tid >> 6) & 15;
    const int ms = tid >> 10;
    const int m = ms * 16 + (lane & 15);
    const int k = ks * 32 + (lane >> 4) * 8;
    const float* src = brep + m * 512 + k;
    unsigned short hb[8];
    #pragma unroll
    for (int j = 0; j < 8; j++) {
        f16 v = (f16)src[j];
        hb[j] = __builtin_bit_cast(unsigned short, v);
    }
    uint4 o;
    o.x = (unsigned)hb[0] | ((unsigned)hb[1] << 16);
    o.y = (unsigned)hb[2] | ((unsigned)hb[3] << 16);
    o.z = (unsigned)hb[4] | ((unsigned)hb[5] << 16);
    o.w = (unsigned)hb[6] | ((unsigned)hb[7] << 16);
    xfrag[tid] = o;
}

// ---------------------------------------------------------------------------
// Kernel 1: streaming distance scores + per-block top-16 per batch row.
// s(n) = ||y_n||^2 - 2 * x.y_n   (f16 MFMA dot; ||x||^2 constant per row, omitted)
// Tile = 64 reps rows; K chunked by 64 floats staged fp32 into LDS via
// global_load_lds (linear dest, 1040B group stride for bank spread).
// ---------------------------------------------------------------------------
__global__ __launch_bounds__(256) void dist_topk_kernel(
    const float* __restrict__ reps, const uint4* __restrict__ xfrag,
    float* __restrict__ cs, int* __restrict__ ci,
    int N, int tilesBase, int tilesRem)
{
    // ylds: 16 groups x (4 rows x 64 floats + 4 pad floats) = 4160 floats
    __shared__ __align__(16) float ylds[16 * 260];
    __shared__ __align__(16) float slds[64][68];      // [n_local][m]
    __shared__ float topd[16][64];                    // [slot][row]
    __shared__ int   topi[16][64];
    __shared__ float ynorm_s[64];
    __shared__ float ynp[64][4];

    const int tid = threadIdx.x;
    const int w = tid >> 6, lane = tid & 63;
    const int wm = w >> 1, wn = w & 1;
    const int b = blockIdx.x;
    const int t0 = b * tilesBase + min(b, tilesRem);
    const int tcount = tilesBase + (b < tilesRem ? 1 : 0);

    float thr = INF_F; int thrn = 0x7fffffff; int cnt = 0;

    const int yr = tid & 63;   // ynorm row
    const int yq = tid >> 6;   // ynorm quarter (16 floats per chunk)

    for (int ti = 0; ti < tcount; ti++) {
        const int n0 = (t0 + ti) * 64;
        f32x4 acc[2][2];
        #pragma unroll
        for (int s = 0; s < 2; s++)
            #pragma unroll
            for (int t = 0; t < 2; t++)
                acc[s][t] = (f32x4){0.f, 0.f, 0.f, 0.f};
        float ynacc = 0.f;

        for (int kc8 = 0; kc8 < 8; kc8++) {
            const int kc = kc8 * 64;
            __syncthreads();   // ylds free (prev chunk consumed / scan of prev tile done)
            // ---- stage 16KB: 4 global_load_lds (1KB each) per wave ----
            #pragma unroll
            for (int i = 0; i < 4; i++) {
                const int q = w * 4 + i;                 // 0..15, rows 4q..4q+3
                const int r = q * 4 + (lane >> 4);
                long ng = (long)n0 + r;
                if (ng >= (long)N) ng = 0;               // safe pad row (excluded in scan)
                const float* src = reps + ng * 512 + kc + (lane & 15) * 4;
                GLOAD_LDS16(src, (char*)ylds + q * 1040);
            }
            __syncthreads();
            // ---- ynorm partial: row yr, 16 floats (quarter yq) of this chunk ----
            {
                const float* rowp = ylds + (yr >> 2) * 260 + (yr & 3) * 64;
                #pragma unroll
                for (int i = 0; i < 4; i++) {
                    float4 v = *(const float4*)(rowp + (yq * 4 + i) * 4);
                    ynacc = fmaf(v.x, v.x, fmaf(v.y, v.y, fmaf(v.z, v.z, fmaf(v.w, v.w, ynacc))));
                }
            }
            // ---- MFMA: 2 k-steps of 32 per chunk ----
            #pragma unroll
            for (int ksl = 0; ksl < 2; ksl++) {
                const int ks = kc8 * 2 + ksl;
                uint4 a0u = xfrag[((2 * wm) * 16 + ks) * 64 + lane];
                uint4 a1u = xfrag[((2 * wm + 1) * 16 + ks) * 64 + lane];
                f16x8 af0 = __builtin_bit_cast(f16x8, a0u);
                f16x8 af1 = __builtin_bit_cast(f16x8, a1u);
                #pragma unroll
                for (int t = 0; t < 2; t++) {
                    const int r = 32 * wn + 16 * t + (lane & 15);
                    const int cb = ksl * 8 + (lane >> 4) * 2;   // 16B-chunk index in row
                    const float* rowp = ylds + (r >> 2) * 260 + (r & 3) * 64 + cb * 4;
                    float4 y0 = *(const float4*)(rowp);
                    float4 y1 = *(const float4*)(rowp + 4);
                    f16x8 bf;
                    bf[0] = (f16)y0.x; bf[1] = (f16)y0.y; bf[2] = (f16)y0.z; bf[3] = (f16)y0.w;
                    bf[4] = (f16)y1.x; bf[5] = (f16)y1.y; bf[6] = (f16)y1.z; bf[7] = (f16)y1.w;
                    acc[0][t] = __builtin_amdgcn_mfma_f32_16x16x32_f16(af0, bf, acc[0][t], 0, 0, 0);
                    acc[1][t] = __builtin_amdgcn_mfma_f32_16x16x32_f16(af1, bf, acc[1][t], 0, 0, 0);
                }
            }
        }
        // ---- finalize ||y||^2 (fixed deterministic tree) ----
        ynp[yr][yq] = ynacc;
        __syncthreads();
        if (tid < 64)
            ynorm_s[tid] = (ynp[tid][0] + ynp[tid][1]) + (ynp[tid][2] + ynp[tid][3]);
        __syncthreads();
        // ---- write s = ||y||^2 - 2 dot to slds[n][m] ----
        #pragma unroll
        for (int s = 0; s < 2; s++) {
            #pragma unroll
            for (int t = 0; t < 2; t++) {
                const int nl = 32 * wn + 16 * t + (lane & 15);
                const float yn = ynorm_s[nl];
                const int mbase = 16 * (2 * wm + s) + 4 * (lane >> 4);
                float4 sv;
                sv.x = fmaf(-2.f, acc[s][t][0], yn);
                sv.y = fmaf(-2.f, acc[s][t][1], yn);
                sv.z = fmaf(-2.f, acc[s][t][2], yn);
                sv.w = fmaf(-2.f, acc[s][t][3], yn);
                *(float4*)(&slds[nl][mbase]) = sv;
            }
        }
        __syncthreads();
        // ---- per-row top-16 scan (thread r owns batch row r; register threshold) ----
        if (tid < 64) {
            const int r = tid;
            for (int j = 0; j < 64; j++) {
                const int n = n0 + j;
                if (n >= N) break;
                const float s = slds[j][r];
                if (lexLess(s, n, thr, thrn)) {
                    if (cnt < 16) {
                        topd[cnt][r] = s; topi[cnt][r] = n; cnt++;
                        if (cnt == 16) {
                            float tv = topd[0][r]; int tn = topi[0][r];
                            #pragma unroll
                            for (int q = 1; q < 16; q++) {
                                float v = topd[q][r]; int nn = topi[q][r];
                                if (!lexLess(v, nn, tv, tn)) { tv = v; tn = nn; }
                            }
                            thr = tv; thrn = tn;
                        }
                    } else {
                        #pragma unroll
                        for (int q = 0; q < 16; q++)
                            if (topd[q][r] == thr && topi[q][r] == thrn) {
                                topd[q][r] = s; topi[q][r] = n; break;
                            }
                        float tv = topd[0][r]; int tn = topi[0][r];
                        #pragma unroll
                        for (int q = 1; q < 16; q++) {
                            float v = topd[q][r]; int nn = topi[q][r];
                            if (!lexLess(v, nn, tv, tn)) { tv = v; tn = nn; }
                        }
                        thr = tv; thrn = tn;
                    }
                }
            }
        }
        // next tile's first __syncthreads orders scan before ylds/slds reuse
    }

    if (tid < 64) {
        const size_t base = ((size_t)b * 64 + tid) * 16;
        for (int j = 0; j < 16; j++) {
            cs[base + j] = (j < cnt) ? topd[j][tid] : INF_F;
            ci[base + j] = (j < cnt) ? topi[j][tid] : 0x7fffffff;
        }
    }
}

// ---------------------------------------------------------------------------
// Kernel 2: per batch row — approx global top-24 merge, fp64 exact recompute,
// exact sort -> top-16, softmax weights, action gather, outputs.
// ---------------------------------------------------------------------------
__global__ __launch_bounds__(256) void merge_kernel(
    const float* __restrict__ cs, const int* __restrict__ ci,
    const float* __restrict__ brep, const float* __restrict__ reps,
    const float* __restrict__ acts,
    float* __restrict__ out, int NBLK, int N, int BA)
{
    const int r = blockIdx.x;
    const int tid = threadIdx.x;
    __shared__ __align__(16) float xrow[512];
    __shared__ float S1s[256 * KM];
    __shared__ int   S1i[256 * KM];
    __shared__ float S2s[32 * KM];
    __shared__ int   S2i[32 * KM];
    __shared__ double fd[KM];
    __shared__ int    fn[KM];

    if (tid < 128)
        *(float4*)(&xrow[tid * 4]) = *(const float4*)(&brep[(size_t)r * 512 + tid * 4]);

    // ---- stage 1: strided scan, per-thread approx top-KM (replace-max) ----
    float ls[KM]; int li[KM];
    #pragma unroll
    for (int j = 0; j < KM; j++) { ls[j] = INF_F; li[j] = 0x7fffffff; }
    float mv = INF_F; int mn = 0x7fffffff; int mp = 0;
    const int total = NBLK * 16;
    for (int e = tid; e < total; e += 256) {
        const int blk = e >> 4, j = e & 15;
        const size_t a = (size_t)blk * 1024 + (size_t)r * 16 + j;
        const float s = cs[a]; const int n = ci[a];
        if (lexLess(s, n, mv, mn)) {
            ls[mp] = s; li[mp] = n;
            mv = ls[0]; mn = li[0]; mp = 0;
            #pragma unroll
            for (int q = 1; q < KM; q++)
                if (!lexLess(ls[q], li[q], mv, mn)) { mv = ls[q]; mn = li[q]; mp = q; }
        }
    }
    #pragma unroll
    for (int j = 0; j < KM; j++) { S1s[tid * KM + j] = ls[j]; S1i[tid * KM + j] = li[j]; }
    __syncthreads();

    // ---- stage 2: 32 threads merge 8 lists each ----
    if (tid < 32) {
        #pragma unroll
        for (int j = 0; j < KM; j++) { ls[j] = INF_F; li[j] = 0x7fffffff; }
        mv = INF_F; mn = 0x7fffffff; mp = 0;
        for (int e = tid * 8 * KM; e < (tid * 8 + 8) * KM; e++) {
            const float s = S1s[e]; const int n = S1i[e];
            if (lexLess(s, n, mv, mn)) {
                ls[mp] = s; li[mp] = n;
                mv = ls[0]; mn = li[0]; mp = 0;
                #pragma unroll
                for (int q = 1; q < KM; q++)
                    if (!lexLess(ls[q], li[q], mv, mn)) { mv = ls[q]; mn = li[q]; mp = q; }
            }
        }
        #pragma unroll
        for (int j = 0; j < KM; j++) { S2s[tid * KM + j] = ls[j]; S2i[tid * KM + j] = li[j]; }
    }
    __syncthreads();

    // ---- stage 3: thread 0 -> approx top-KM (membership only) ----
    if (tid == 0) {
        #pragma unroll
        for (int j = 0; j < KM; j++) { ls[j] = INF_F; li[j] = 0x7fffffff; }
        mv = INF_F; mn = 0x7fffffff; mp = 0;
        for (int e = 0; e < 32 * KM; e++) {
            const float s = S2s[e]; const int n = S2i[e];
            if (lexLess(s, n, mv, mn)) {
                ls[mp] = s; li[mp] = n;
                mv = ls[0]; mn = li[0]; mp = 0;
                #pragma unroll
                for (int q = 1; q < KM; q++)
                    if (!lexLess(ls[q], li[q], mv, mn)) { mv = ls[q]; mn = li[q]; mp = q; }
            }
        }
        for (int j = 0; j < KM; j++) fn[j] = li[j];
    }
    __syncthreads();

    // ---- fp64 exact recompute of the KM candidates ----
    if (tid < KM) {
        const int n = fn[tid];
        double d = 1.0e300;
        if (n >= 0 && n < N) {
            d = 0.0;
            const float* yp = reps + (size_t)n * 512;
            for (int i = 0; i < 512; i += 4) {
                float4 yv = *(const float4*)(yp + i);
                double d0 = (double)xrow[i + 0] - (double)yv.x;
                double d1 = (double)xrow[i + 1] - (double)yv.y;
                double d2 = (double)xrow[i + 2] - (double)yv.z;
                double d3 = (double)xrow[i + 3] - (double)yv.w;
                d += d0 * d0 + d1 * d1 + d2 * d2 + d3 * d3;
            }
        }
        fd[tid] = d;
    }
    __syncthreads();

    // ---- exact sort (d, n) lexicographic, take 16, outputs ----
    if (tid == 0) {
        int ord[KM];
        for (int j = 0; j < KM; j++) ord[j] = j;
        for (int a = 0; a < 16; a++) {
            int best = a;
            for (int q = a + 1; q < KM; q++) {
                const int oq = ord[q], ob = ord[best];
                if (fd[oq] < fd[ob] || (fd[oq] == fd[ob] && fn[oq] < fn[ob])) best = q;
            }
            int tmp = ord[a]; ord[a] = ord[best]; ord[best] = tmp;
        }
        double dist[16];
        for (int j = 0; j < 16; j++) {
            double v = fd[ord[j]];
            dist[j] = sqrt(v > 0.0 ? v : 0.0);
        }
        double wv[16], wsum = 0.0;
        for (int j = 0; j < 16; j++) { wv[j] = exp(dist[0] - dist[j]); wsum += wv[j]; }
        for (int a = 0; a < 7; a++) {
            double s = 0.0;
            for (int j = 0; j < 16; j++)
                s += wv[j] * (double)acts[(size_t)fn[ord[j]] * 7 + a];
            out[r * 7 + a] = (float)(s / wsum);
        }
        for (int j = 0; j < 16; j++)
            out[BA + r * 16 + j] = (float)fn[ord[j]];
    }
}

extern "C" void kernel_launch(void* const* d_in, const int* in_sizes, int n_in,
                              void* d_out, int out_size, void* d_ws, size_t ws_size,
                              hipStream_t stream) {
    const float* brep = (const float*)d_in[0];
    const float* reps = (const float*)d_in[1];
    const float* acts = (const float*)d_in[2];
    const int D = 512;
    const int B = in_sizes[0] / D;   // 64
    const int N = in_sizes[1] / D;   // 500000
    float* out = (float*)d_out;

    // workspace: cs [NBLK*64*16 f32] | ci [NBLK*64*16 i32] | xfrag [64KB]
    int NBLK = 768;                                   // 3 blocks/CU
    const size_t perblk = (size_t)64 * 16 * 8;
    if ((size_t)NBLK * perblk + 65536 > ws_size)
        NBLK = (int)((ws_size - 65536) / perblk);
    if (NBLK < 1) NBLK = 1;

    float* cs = (float*)d_ws;
    int* ci = (int*)((char*)d_ws + (size_t)NBLK * 64 * 16 * 4);
    uint4* xfrag = (uint4*)((char*)d_ws + (size_t)NBLK * perblk);

    const int TT = (N + 63) / 64;                     // 64-row tiles
    const int tilesBase = TT / NBLK;
    const int tilesRem = TT % NBLK;

    prepack_kernel<<<16, 256, 0, stream>>>(brep, xfrag);
    dist_topk_kernel<<<NBLK, 256, 0, stream>>>(reps, xfrag, cs, ci, N, tilesBase, tilesRem);
    merge_kernel<<<B, 256, 0, stream>>>(cs, ci, brep, reps, acts, out, NBLK, N, B * 7);
}

// Round 4
// 1552.728 us; speedup vs baseline: 4.6551x; 1.0139x over previous
//
#include <hip/hip_runtime.h>
#include <stdint.h>

typedef _Float16 f16;
typedef _Float16 f16x8 __attribute__((ext_vector_type(8)));
typedef float f32x4 __attribute__((ext_vector_type(4)));

#define INF_F __builtin_inff()
#define KM 24   // merge candidate margin

__device__ __forceinline__ bool lexLess(float s1, int n1, float s2, int n2) {
    return (s1 < s2) || (s1 == s2 && n1 < n2);
}

// ---------------------------------------------------------------------------
// Kernel 0: pack brep [64,512] f32 -> f16 MFMA A-fragments.
// Layout: xfrag[(ks*64 + lane)*4 + ms] = uint4 holding A[m=ms*16+(lane&15)]
// [k = ks*32 + (lane>>4)*8 + j], j=0..7.  (64 KB total, L1/L2-hot.)
// ---------------------------------------------------------------------------
__global__ __launch_bounds__(256) void prepack_kernel(
    const float* __restrict__ brep, uint4* __restrict__ xfrag)
{
    const int e = blockIdx.x * 256 + threadIdx.x;   // 0..4095
    if (e >= 4096) return;
    const int ms = e & 3;
    const int lane = (e >> 2) & 63;
    const int ks = e >> 8;
    const int m = ms * 16 + (lane & 15);
    const int k = ks * 32 + (lane >> 4) * 8;
    const float* src = brep + m * 512 + k;
    unsigned short hb[8];
    #pragma unroll
    for (int j = 0; j < 8; j++) {
        f16 v = (f16)src[j];                         // RTN
        hb[j] = __builtin_bit_cast(unsigned short, v);
    }
    uint4 o;
    o.x = (unsigned)hb[0] | ((unsigned)hb[1] << 16);
    o.y = (unsigned)hb[2] | ((unsigned)hb[3] << 16);
    o.z = (unsigned)hb[4] | ((unsigned)hb[5] << 16);
    o.w = (unsigned)hb[6] | ((unsigned)hb[7] << 16);
    xfrag[e] = o;
}

// ---------------------------------------------------------------------------
// Kernel 1: barrier-free-k-loop streaming scores + per-block top-16 per row.
// Wave w of a block owns reps rows [n0+16w, n0+16w+16): B-fragments loaded
// straight global->VGPR (no LDS staging), f32->f16 via cvt_pkrtz, 4 MFMAs/ks
// vs register A-fragments fetched from L2-hot xfrag. ||y||^2 in f32 from the
// same loads. s = ||y||^2 - 2 x.y lands in LDS [n][m]; 64-thread scan keeps
// exact per-block top-16 per batch row (lexicographic (s, idx)).
// ---------------------------------------------------------------------------
__global__ __launch_bounds__(256, 3) void dist_topk_kernel(
    const float* __restrict__ reps, const uint4* __restrict__ xfrag,
    float* __restrict__ cs, int* __restrict__ ci,
    int N, int tilesBase, int tilesRem)
{
    __shared__ __align__(16) float slds[64][68];
    __shared__ float topd[16][64];
    __shared__ int   topi[16][64];

    const int tid = threadIdx.x;
    const int w = tid >> 6, lane = tid & 63;
    const int li = lane & 15, q = lane >> 4;
    const int b = blockIdx.x;
    const int t0 = b * tilesBase + min(b, tilesRem);
    const int tcount = tilesBase + (b < tilesRem ? 1 : 0);

    float thr = INF_F; int thrn = 0x7fffffff; int cnt = 0;

    for (int ti = 0; ti < tcount; ti++) {
        const int n0 = (t0 + ti) * 64;
        const int row = n0 + 16 * w + li;
        const size_t rowc = (size_t)(row < N ? row : N - 1);
        const float* bp = reps + rowc * 512 + q * 8;

        f32x4 acc0 = {0.f,0.f,0.f,0.f}, acc1 = {0.f,0.f,0.f,0.f};
        f32x4 acc2 = {0.f,0.f,0.f,0.f}, acc3 = {0.f,0.f,0.f,0.f};
        float ynacc = 0.f;

        #pragma unroll 2
        for (int ks = 0; ks < 16; ks++) {
            const float4 y0 = *(const float4*)(bp + ks * 32);
            const float4 y1 = *(const float4*)(bp + ks * 32 + 4);
            const uint4* ap = xfrag + (((size_t)ks * 64 + lane) << 2);
            const uint4 a0u = ap[0];
            const uint4 a1u = ap[1];
            const uint4 a2u = ap[2];
            const uint4 a3u = ap[3];
            ynacc = fmaf(y0.x, y0.x, fmaf(y0.y, y0.y, fmaf(y0.z, y0.z, fmaf(y0.w, y0.w, ynacc))));
            ynacc = fmaf(y1.x, y1.x, fmaf(y1.y, y1.y, fmaf(y1.z, y1.z, fmaf(y1.w, y1.w, ynacc))));
            const auto p0 = __builtin_amdgcn_cvt_pkrtz(y0.x, y0.y);
            const auto p1 = __builtin_amdgcn_cvt_pkrtz(y0.z, y0.w);
            const auto p2 = __builtin_amdgcn_cvt_pkrtz(y1.x, y1.y);
            const auto p3 = __builtin_amdgcn_cvt_pkrtz(y1.z, y1.w);
            uint4 bu;
            bu.x = __builtin_bit_cast(unsigned, p0);
            bu.y = __builtin_bit_cast(unsigned, p1);
            bu.z = __builtin_bit_cast(unsigned, p2);
            bu.w = __builtin_bit_cast(unsigned, p3);
            const f16x8 bf = __builtin_bit_cast(f16x8, bu);
            acc0 = __builtin_amdgcn_mfma_f32_16x16x32_f16(__builtin_bit_cast(f16x8, a0u), bf, acc0, 0, 0, 0);
            acc1 = __builtin_amdgcn_mfma_f32_16x16x32_f16(__builtin_bit_cast(f16x8, a1u), bf, acc1, 0, 0, 0);
            acc2 = __builtin_amdgcn_mfma_f32_16x16x32_f16(__builtin_bit_cast(f16x8, a2u), bf, acc2, 0, 0, 0);
            acc3 = __builtin_amdgcn_mfma_f32_16x16x32_f16(__builtin_bit_cast(f16x8, a3u), bf, acc3, 0, 0, 0);
        }
        // full ||y||^2 for this lane's row (reduce across the 4 k-quarters)
        ynacc += __shfl_xor(ynacc, 16);
        ynacc += __shfl_xor(ynacc, 32);
        const float yn = (row < N) ? ynacc : INF_F;   // invalid rows -> +inf s

        __syncthreads();   // A: previous tile's scan has finished with slds

        // D layout: col n = lane&15, row m(within 16) = 4*q + reg
        {
            const int nl = 16 * w + li;
            float4 sv;
            sv.x = fmaf(-2.f, acc0[0], yn); sv.y = fmaf(-2.f, acc0[1], yn);
            sv.z = fmaf(-2.f, acc0[2], yn); sv.w = fmaf(-2.f, acc0[3], yn);
            *(float4*)(&slds[nl][0  + 4 * q]) = sv;
            sv.x = fmaf(-2.f, acc1[0], yn); sv.y = fmaf(-2.f, acc1[1], yn);
            sv.z = fmaf(-2.f, acc1[2], yn); sv.w = fmaf(-2.f, acc1[3], yn);
            *(float4*)(&slds[nl][16 + 4 * q]) = sv;
            sv.x = fmaf(-2.f, acc2[0], yn); sv.y = fmaf(-2.f, acc2[1], yn);
            sv.z = fmaf(-2.f, acc2[2], yn); sv.w = fmaf(-2.f, acc2[3], yn);
            *(float4*)(&slds[nl][32 + 4 * q]) = sv;
            sv.x = fmaf(-2.f, acc3[0], yn); sv.y = fmaf(-2.f, acc3[1], yn);
            sv.z = fmaf(-2.f, acc3[2], yn); sv.w = fmaf(-2.f, acc3[3], yn);
            *(float4*)(&slds[nl][48 + 4 * q]) = sv;
        }
        __syncthreads();   // B: s-matrix ready

        // per-row top-16 scan; thread r owns batch row r (register threshold)
        if (tid < 64) {
            const int r = tid;
            #pragma unroll 4
            for (int j = 0; j < 64; j++) {
                const float s = slds[j][r];
                const int n = n0 + j;
                if (lexLess(s, n, thr, thrn)) {
                    if (cnt < 16) {
                        topd[cnt][r] = s; topi[cnt][r] = n; cnt++;
                        if (cnt == 16) {
                            float tv = topd[0][r]; int tn = topi[0][r];
                            #pragma unroll
                            for (int u = 1; u < 16; u++) {
                                float v = topd[u][r]; int nn = topi[u][r];
                                if (!lexLess(v, nn, tv, tn)) { tv = v; tn = nn; }
                            }
                            thr = tv; thrn = tn;
                        }
                    } else {
                        #pragma unroll
                        for (int u = 0; u < 16; u++)
                            if (topd[u][r] == thr && topi[u][r] == thrn) {
                                topd[u][r] = s; topi[u][r] = n; break;
                            }
                        float tv = topd[0][r]; int tn = topi[0][r];
                        #pragma unroll
                        for (int u = 1; u < 16; u++) {
                            float v = topd[u][r]; int nn = topi[u][r];
                            if (!lexLess(v, nn, tv, tn)) { tv = v; tn = nn; }
                        }
                        thr = tv; thrn = tn;
                    }
                }
            }
        }
    }

    if (tid < 64) {
        const size_t base = ((size_t)b * 64 + tid) * 16;
        for (int j = 0; j < 16; j++) {
            cs[base + j] = (j < cnt) ? topd[j][tid] : INF_F;
            ci[base + j] = (j < cnt) ? topi[j][tid] : 0x7fffffff;
        }
    }
}

// ---------------------------------------------------------------------------
// Kernel 2: per batch row — approx global top-24 merge, fp64 exact recompute,
// exact sort -> top-16, softmax weights, action gather, outputs.
// ---------------------------------------------------------------------------
__global__ __launch_bounds__(256) void merge_kernel(
    const float* __restrict__ cs, const int* __restrict__ ci,
    const float* __restrict__ brep, const float* __restrict__ reps,
    const float* __restrict__ acts,
    float* __restrict__ out, int NBLK, int N, int BA)
{
    const int r = blockIdx.x;
    const int tid = threadIdx.x;
    __shared__ __align__(16) float xrow[512];
    __shared__ float S1s[256 * KM];
    __shared__ int   S1i[256 * KM];
    __shared__ float S2s[32 * KM];
    __shared__ int   S2i[32 * KM];
    __shared__ double fd[KM];
    __shared__ int    fn[KM];

    if (tid < 128)
        *(float4*)(&xrow[tid * 4]) = *(const float4*)(&brep[(size_t)r * 512 + tid * 4]);

    float ls[KM]; int li[KM];
    #pragma unroll
    for (int j = 0; j < KM; j++) { ls[j] = INF_F; li[j] = 0x7fffffff; }
    float mv = INF_F; int mn = 0x7fffffff; int mp = 0;
    const int total = NBLK * 16;
    for (int e = tid; e < total; e += 256) {
        const int blk = e >> 4, j = e & 15;
        const size_t a = (size_t)blk * 1024 + (size_t)r * 16 + j;
        const float s = cs[a]; const int n = ci[a];
        if (lexLess(s, n, mv, mn)) {
            ls[mp] = s; li[mp] = n;
            mv = ls[0]; mn = li[0]; mp = 0;
            #pragma unroll
            for (int u = 1; u < KM; u++)
                if (!lexLess(ls[u], li[u], mv, mn)) { mv = ls[u]; mn = li[u]; mp = u; }
        }
    }
    #pragma unroll
    for (int j = 0; j < KM; j++) { S1s[tid * KM + j] = ls[j]; S1i[tid * KM + j] = li[j]; }
    __syncthreads();

    if (tid < 32) {
        #pragma unroll
        for (int j = 0; j < KM; j++) { ls[j] = INF_F; li[j] = 0x7fffffff; }
        mv = INF_F; mn = 0x7fffffff; mp = 0;
        for (int e = tid * 8 * KM; e < (tid * 8 + 8) * KM; e++) {
            const float s = S1s[e]; const int n = S1i[e];
            if (lexLess(s, n, mv, mn)) {
                ls[mp] = s; li[mp] = n;
                mv = ls[0]; mn = li[0]; mp = 0;
                #pragma unroll
                for (int u = 1; u < KM; u++)
                    if (!lexLess(ls[u], li[u], mv, mn)) { mv = ls[u]; mn = li[u]; mp = u; }
            }
        }
        #pragma unroll
        for (int j = 0; j < KM; j++) { S2s[tid * KM + j] = ls[j]; S2i[tid * KM + j] = li[j]; }
    }
    __syncthreads();

    if (tid == 0) {
        #pragma unroll
        for (int j = 0; j < KM; j++) { ls[j] = INF_F; li[j] = 0x7fffffff; }
        mv = INF_F; mn = 0x7fffffff; mp = 0;
        for (int e = 0; e < 32 * KM; e++) {
            const float s = S2s[e]; const int n = S2i[e];
            if (lexLess(s, n, mv, mn)) {
                ls[mp] = s; li[mp] = n;
                mv = ls[0]; mn = li[0]; mp = 0;
                #pragma unroll
                for (int u = 1; u < KM; u++)
                    if (!lexLess(ls[u], li[u], mv, mn)) { mv = ls[u]; mn = li[u]; mp = u; }
            }
        }
        for (int j = 0; j < KM; j++) fn[j] = li[j];
    }
    __syncthreads();

    if (tid < KM) {
        const int n = fn[tid];
        double d = 1.0e300;
        if (n >= 0 && n < N) {
            d = 0.0;
            const float* yp = reps + (size_t)n * 512;
            for (int i = 0; i < 512; i += 4) {
                float4 yv = *(const float4*)(yp + i);
                double d0 = (double)xrow[i + 0] - (double)yv.x;
                double d1 = (double)xrow[i + 1] - (double)yv.y;
                double d2 = (double)xrow[i + 2] - (double)yv.z;
                double d3 = (double)xrow[i + 3] - (double)yv.w;
                d += d0 * d0 + d1 * d1 + d2 * d2 + d3 * d3;
            }
        }
        fd[tid] = d;
    }
    __syncthreads();

    if (tid == 0) {
        int ord[KM];
        for (int j = 0; j < KM; j++) ord[j] = j;
        for (int a = 0; a < 16; a++) {
            int best = a;
            for (int u = a + 1; u < KM; u++) {
                const int ou = ord[u], ob = ord[best];
                if (fd[ou] < fd[ob] || (fd[ou] == fd[ob] && fn[ou] < fn[ob])) best = u;
            }
            int tmp = ord[a]; ord[a] = ord[best]; ord[best] = tmp;
        }
        double dist[16];
        for (int j = 0; j < 16; j++) {
            double v = fd[ord[j]];
            dist[j] = sqrt(v > 0.0 ? v : 0.0);
        }
        double wv[16], wsum = 0.0;
        for (int j = 0; j < 16; j++) { wv[j] = exp(dist[0] - dist[j]); wsum += wv[j]; }
        for (int a = 0; a < 7; a++) {
            double s = 0.0;
            for (int j = 0; j < 16; j++)
                s += wv[j] * (double)acts[(size_t)fn[ord[j]] * 7 + a];
            out[r * 7 + a] = (float)(s / wsum);
        }
        for (int j = 0; j < 16; j++)
            out[BA + r * 16 + j] = (float)fn[ord[j]];
    }
}

extern "C" void kernel_launch(void* const* d_in, const int* in_sizes, int n_in,
                              void* d_out, int out_size, void* d_ws, size_t ws_size,
                              hipStream_t stream) {
    const float* brep = (const float*)d_in[0];
    const float* reps = (const float*)d_in[1];
    const float* acts = (const float*)d_in[2];
    const int D = 512;
    const int B = in_sizes[0] / D;   // 64
    const int N = in_sizes[1] / D;   // 500000
    float* out = (float*)d_out;

    // workspace: cs [NBLK*64*16 f32] | ci [NBLK*64*16 i32] | xfrag [64KB]
    int NBLK = 1536;                                  // 2 rounds of 3 blocks/CU
    const size_t perblk = (size_t)64 * 16 * 8;
    if ((size_t)NBLK * perblk + 65536 > ws_size)
        NBLK = (int)((ws_size - 65536) / perblk);
    if (NBLK < 1) NBLK = 1;

    float* cs = (float*)d_ws;
    int* ci = (int*)((char*)d_ws + (size_t)NBLK * 64 * 16 * 4);
    uint4* xfrag = (uint4*)((char*)d_ws + (size_t)NBLK * perblk);

    const int TT = (N + 63) / 64;                     // 64-row tiles
    const int tilesBase = TT / NBLK;
    const int tilesRem = TT % NBLK;

    prepack_kernel<<<16, 256, 0, stream>>>(brep, xfrag);
    dist_topk_kernel<<<NBLK, 256, 0, stream>>>(reps, xfrag, cs, ci, N, tilesBase, tilesRem);
    merge_kernel<<<B, 256, 0, stream>>>(cs, ci, brep, reps, acts, out, NBLK, N, B * 7);
}